// Round 2
// baseline (424.110 us; speedup 1.0000x reference)
//
#include <hip/hip_runtime.h>
#include <hip/hip_bf16.h>
#include <math.h>

// MultiBoxLoss: B=64, P=16800, G=32, C=2.
// init -> k_prior (IoU once: per-prior best-truth stored + per-gt best-prior via
// wave-reduce + atomicMax(u64)) -> k_match (no IoU; losses + bc) ->
// k_select (per-batch exact top-k radix) -> k_final.

#define RCP(x) __builtin_amdgcn_rcpf(x)

__device__ __forceinline__ float sl1(float x) {
    float ax = fabsf(x);
    return ax < 1.f ? 0.5f * ax * ax : ax - 0.5f;
}

// block-wide sum, blockDim.x == 256. Result valid on all threads.
__device__ __forceinline__ float block_sum256(float v, float* buf) {
    #pragma unroll
    for (int o = 32; o > 0; o >>= 1) v += __shfl_down(v, o, 64);
    int lane = threadIdx.x & 63, w = threadIdx.x >> 6;
    __syncthreads();
    if (lane == 0) buf[w] = v;
    __syncthreads();
    return buf[0] + buf[1] + buf[2] + buf[3];
}

__global__ void k_init(int* __restrict__ p, int n) {
    int i = blockIdx.x * 256 + threadIdx.x;
    if (i < n) p[i] = 0;
}

// ---- k_prior: one thread per (b,p). Computes all G IoUs ONCE.
//  - per-prior best-truth (max over g, first idx) -> btv/bti (if STORE)
//  - per-gt best-prior: packed key (iou<<32 | ~p), wave shuffle-reduce,
//    one atomicMax per wave per gt. ~p makes ties pick the SMALLEST p.
template<int GN, bool STORE>
__global__ __launch_bounds__(256)
void k_prior(const float4* __restrict__ priors, const float* __restrict__ targets,
             unsigned long long* __restrict__ keys, float* __restrict__ btv,
             unsigned char* __restrict__ bti, int P) {
    int b = blockIdx.y, tid = threadIdx.x;
    int p = blockIdx.x * 256 + tid;
    __shared__ float4 s_box[GN];
    for (int i = tid; i < GN; i += 256) {
        const float* t = targets + ((size_t)b * GN + i) * 15;
        s_box[i] = make_float4(t[0], t[1], t[2], t[3]);
    }
    __syncthreads();
    bool act = p < P;
    float4 pr = act ? priors[p] : make_float4(4e9f, 4e9f, 0.f, 0.f);
    float px0 = pr.x - pr.z * 0.5f, py0 = pr.y - pr.w * 0.5f;
    float px1 = pr.x + pr.z * 0.5f, py1 = pr.y + pr.w * 0.5f;
    float area_p = (px1 - px0) * (py1 - py0);
    float btv_r = -1.f;
    int bti_r = 0;
    unsigned npk = ~(unsigned)p;
    #pragma unroll
    for (int g = 0; g < GN; ++g) {
        float4 tb = s_box[g];
        float lx = fmaxf(tb.x, px0), ly = fmaxf(tb.y, py0);
        float rx = fminf(tb.z, px1), ry = fminf(tb.w, py1);
        float w = fmaxf(rx - lx, 0.f), h = fmaxf(ry - ly, 0.f);
        float inter = w * h;
        float at = (tb.z - tb.x) * (tb.w - tb.y);
        float iou = inter * RCP(at + area_p - inter);
        if (iou > btv_r) { btv_r = iou; bti_r = g; }
        unsigned long long kk =
            act ? (((unsigned long long)__float_as_uint(iou) << 32) | npk) : 0ull;
        #pragma unroll
        for (int o = 32; o > 0; o >>= 1) {
            unsigned long long o2 = __shfl_down(kk, o, 64);
            if (o2 > kk) kk = o2;
        }
        if ((tid & 63) == 0) atomicMax(&keys[b * GN + g], kk);
    }
    if (STORE && act) {
        btv[(size_t)b * P + p] = btv_r;
        bti[(size_t)b * P + p] = (unsigned char)bti_r;
    }
}

// ---- k_match: forced-match override + conf + per-element losses ----
template<int GN, bool STORED>
__global__ __launch_bounds__(256)
void k_match(const float2* __restrict__ cls, const float4* __restrict__ loc,
             const float* __restrict__ lmd, const float4* __restrict__ priors,
             const float* __restrict__ targets,
             const unsigned long long* __restrict__ keys,
             const float* __restrict__ btvA, const unsigned char* __restrict__ btiA,
             float* __restrict__ bc, int* __restrict__ npos,
             int* __restrict__ icnt, float* __restrict__ facc, int P) {
    int b = blockIdx.y, tid = threadIdx.x;
    int p = blockIdx.x * 256 + tid;
    __shared__ float s_t[GN * 4];
    __shared__ float s_lm[GN * 10];
    __shared__ float s_lab[GN];
    __shared__ unsigned s_kl[GN];
    __shared__ unsigned s_vm;
    if (tid == 0) s_vm = 0;
    for (int i = tid; i < GN * 15; i += 256) {
        int g = i / 15, j = i - g * 15;
        float v = targets[((size_t)b * GN + g) * 15 + j];
        if (j < 4) s_t[g * 4 + j] = v;
        else if (j < 14) s_lm[g * 10 + (j - 4)] = v;
        else s_lab[g] = v;
    }
    __syncthreads();
    if (tid < GN) {
        unsigned long long kk = keys[b * GN + tid];
        s_kl[tid] = (unsigned)kk;
        if (__uint_as_float((unsigned)(kk >> 32)) >= 0.2f) atomicOr(&s_vm, 1u << tid);
    }
    __syncthreads();
    unsigned vm = s_vm;
    int av = vm != 0;

    float v_ll = 0.f, v_lmm = 0.f, v_lcp = 0.f;
    float n_p = 0.f, n_p1 = 0.f;
    if (p < P) {
        float4 pr = priors[p];
        float btv;
        int bti;
        if constexpr (STORED) {
            btv = btvA[(size_t)b * P + p];
            bti = btiA[(size_t)b * P + p];
        } else {
            float px0 = pr.x - pr.z * 0.5f, py0 = pr.y - pr.w * 0.5f;
            float px1 = pr.x + pr.z * 0.5f, py1 = pr.y + pr.w * 0.5f;
            float area_p = (px1 - px0) * (py1 - py0);
            btv = -1.f; bti = 0;
            #pragma unroll
            for (int g = 0; g < GN; ++g) {
                float tx0 = s_t[g * 4], ty0 = s_t[g * 4 + 1];
                float tx1 = s_t[g * 4 + 2], ty1 = s_t[g * 4 + 3];
                float lx = fmaxf(tx0, px0), ly = fmaxf(ty0, py0);
                float rx = fminf(tx1, px1), ry = fminf(ty1, py1);
                float w = fmaxf(rx - lx, 0.f), h = fmaxf(ry - ly, 0.f);
                float inter = w * h;
                float at = (tx1 - tx0) * (ty1 - ty0);
                float iou = inter * RCP(at + area_p - inter);
                if (iou > btv) { btv = iou; bti = g; }
            }
        }
        unsigned npk = ~(unsigned)p;
        int fidx = -1, fvalid = 0;
        #pragma unroll
        for (int g = 0; g < GN; ++g) {
            if (s_kl[g] == npk) { fidx = g; fvalid |= (int)((vm >> g) & 1u); }
        }
        float btv2 = fvalid ? 2.f : btv;
        int bti2 = fidx >= 0 ? fidx : bti;
        int conf = (av && btv2 >= 0.35f) ? (int)s_lab[bti2] : 0;
        bool pos = conf != 0;

        float2 c = cls[(size_t)b * P + p];
        float m = fmaxf(c.x, c.y);
        float logz = m + __logf(__expf(c.x - m) + __expf(c.y - m));
        float gold = pos ? c.y : c.x;
        float lc = logz - gold;
        bc[(size_t)b * P + p] = pos ? 0.f : lc;

        if (pos) {
            n_p = 1.f; v_lcp = lc;
            float tx0 = s_t[bti2 * 4], ty0 = s_t[bti2 * 4 + 1];
            float tx1 = s_t[bti2 * 4 + 2], ty1 = s_t[bti2 * 4 + 3];
            float rw = RCP(pr.z), rh = RCP(pr.w);
            float lt0 = ((tx0 + tx1) * 0.5f - pr.x) * rw * 10.f;
            float lt1 = ((ty0 + ty1) * 0.5f - pr.y) * rh * 10.f;
            float lt2 = __logf((tx1 - tx0) * rw) * 5.f;
            float lt3 = __logf((ty1 - ty0) * rh) * 5.f;
            float4 ld = loc[(size_t)b * P + p];
            v_ll = sl1(ld.x - lt0) + sl1(ld.y - lt1) + sl1(ld.z - lt2) + sl1(ld.w - lt3);
            if (conf > 0) {
                n_p1 = 1.f;
                const float* lp = lmd + ((size_t)b * P + p) * 10;
                #pragma unroll
                for (int q = 0; q < 5; q++) {
                    float gx = (s_lm[bti2 * 10 + 2 * q]     - pr.x) * rw * 10.f;
                    float gy = (s_lm[bti2 * 10 + 2 * q + 1] - pr.y) * rh * 10.f;
                    v_lmm += sl1(lp[2 * q] - gx) + sl1(lp[2 * q + 1] - gy);
                }
            }
        }
    }
    __shared__ float rbuf[4];
    float bs;
    bs = block_sum256(v_ll, rbuf);
    if (tid == 0 && bs != 0.f) atomicAdd(&facc[0], bs);
    bs = block_sum256(v_lmm, rbuf);
    if (tid == 0 && bs != 0.f) atomicAdd(&facc[1], bs);
    bs = block_sum256(v_lcp, rbuf);
    if (tid == 0 && bs != 0.f) atomicAdd(&facc[2], bs);
    bs = block_sum256(n_p, rbuf);
    if (tid == 0) { int n = (int)(bs + 0.5f); if (n) { atomicAdd(&npos[b], n); atomicAdd(&icnt[0], n); } }
    bs = block_sum256(n_p1, rbuf);
    if (tid == 0) { int n = (int)(bs + 0.5f); if (n) atomicAdd(&icnt[1], n); }
}

// ---- k_select: per-batch sum of k largest bc values (exact radix select) ----
__global__ __launch_bounds__(1024)
void k_select(const float* __restrict__ bc, const int* __restrict__ npos,
              float* __restrict__ facc, int P) {
    int b = blockIdx.x, tid = threadIdx.x;
    const float* v = bc + (size_t)b * P;
    int k = npos[b] * 7;
    if (k > P - 1) k = P - 1;
    if (k <= 0) return;

    __shared__ unsigned hist[256];
    __shared__ unsigned s_pref;
    __shared__ int s_rem;
    unsigned prefix = 0;
    int rem = k;
    for (int shift = 24; shift >= 0; shift -= 8) {
        if (tid < 256) hist[tid] = 0;
        __syncthreads();
        unsigned himask = (shift == 24) ? 0u : (0xFFFFFFFFu << (shift + 8));
        for (int i = tid; i < P; i += 1024) {
            unsigned u = __float_as_uint(v[i]);   // values >= 0: bits order-preserving
            if ((u & himask) == prefix) atomicAdd(&hist[(u >> shift) & 255u], 1u);
        }
        __syncthreads();
        if (tid < 64) {   // wave 0 does the 256-bin suffix scan + pick
            unsigned h0 = hist[tid * 4], h1 = hist[tid * 4 + 1];
            unsigned h2 = hist[tid * 4 + 2], h3 = hist[tid * 4 + 3];
            unsigned gs = h0 + h1 + h2 + h3;
            unsigned suf = gs;
            #pragma unroll
            for (int o = 1; o < 64; o <<= 1) {
                unsigned t = __shfl_down(suf, o, 64);
                if (tid + o < 64) suf += t;
            }
            unsigned ag = suf - gs;                  // count in groups above
            unsigned ca3 = ag, ca2 = ag + h3, ca1 = ca2 + h2, ca0 = ca1 + h1;
            unsigned r = (unsigned)rem;
            if (ca3 < r && r <= ca3 + h3) { s_pref = prefix | (((unsigned)(tid * 4 + 3)) << shift); s_rem = (int)(r - ca3); }
            if (ca2 < r && r <= ca2 + h2) { s_pref = prefix | (((unsigned)(tid * 4 + 2)) << shift); s_rem = (int)(r - ca2); }
            if (ca1 < r && r <= ca1 + h1) { s_pref = prefix | (((unsigned)(tid * 4 + 1)) << shift); s_rem = (int)(r - ca1); }
            if (ca0 < r && r <= ca0 + h0) { s_pref = prefix | (((unsigned)(tid * 4 + 0)) << shift); s_rem = (int)(r - ca0); }
        }
        __syncthreads();
        prefix = s_pref; rem = s_rem;
        __syncthreads();
    }
    float T = __uint_as_float(prefix);               // k-th largest value
    float sum = 0.f; unsigned cnt = 0;
    for (int i = tid; i < P; i += 1024) {
        float x = v[i];
        if (x > T) { sum += x; cnt++; }
    }
    #pragma unroll
    for (int o = 32; o > 0; o >>= 1) {
        sum += __shfl_down(sum, o, 64);
        cnt += __shfl_down(cnt, o, 64);
    }
    __shared__ float ssum[16];
    __shared__ unsigned scnt[16];
    int w = tid >> 6, lane = tid & 63;
    if (lane == 0) { ssum[w] = sum; scnt[w] = cnt; }
    __syncthreads();
    if (tid == 0) {
        float ts = 0.f; unsigned tc = 0;
        #pragma unroll
        for (int i = 0; i < 16; i++) { ts += ssum[i]; tc += scnt[i]; }
        atomicAdd(&facc[3], ts + (float)(k - (int)tc) * T);
    }
}

__global__ void k_final(const float* __restrict__ facc, const int* __restrict__ icnt,
                        float* __restrict__ out) {
    if (threadIdx.x == 0) {
        float N = fmaxf((float)icnt[0], 1.f);
        float N1 = fmaxf((float)icnt[1], 1.f);
        out[0] = facc[0] / N;
        out[1] = (facc[2] + facc[3]) / N;
        out[2] = facc[1] / N1;
    }
}

extern "C" void kernel_launch(void* const* d_in, const int* in_sizes, int n_in,
                              void* d_out, int out_size, void* d_ws, size_t ws_size,
                              hipStream_t stream) {
    const float2* cls    = (const float2*)d_in[0];
    const float4* loc    = (const float4*)d_in[1];
    const float* lmd     = (const float*)d_in[2];
    const float4* priors = (const float4*)d_in[3];
    const float* targets = (const float*)d_in[4];
    int P = in_sizes[3] / 4;
    int B = (in_sizes[1] / 4) / P;
    int G = in_sizes[4] / (15 * B);   // == 32 for this problem

    // ws layout: [keys u64 B*G][npos int B][icnt int 2][facc f32 4][pad][bc][btv][bti]
    size_t off = 0;
    unsigned long long* keys = (unsigned long long*)d_ws; off += (size_t)B * G * 8;
    int* npos  = (int*)((char*)d_ws + off); off += (size_t)B * 4;
    int* icnt  = (int*)((char*)d_ws + off); off += 2 * 4;
    float* facc = (float*)((char*)d_ws + off); off += 4 * 4;
    off = (off + 255) & ~(size_t)255;
    float* bc  = (float*)((char*)d_ws + off); off += (size_t)B * P * 4;
    float* btv = (float*)((char*)d_ws + off); off += (size_t)B * P * 4;
    unsigned char* bti = (unsigned char*)((char*)d_ws + off);
    size_t need = off + (size_t)B * P;
    bool stored = ws_size >= need;

    int nz = B * G * 2 + B + 6;   // keys + npos + icnt + facc, all as ints
    k_init<<<(nz + 255) / 256, 256, 0, stream>>>((int*)d_ws, nz);

    dim3 grid((P + 255) / 256, B);
    if (stored) {
        k_prior<32, true><<<grid, 256, 0, stream>>>(priors, targets, keys, btv, bti, P);
        k_match<32, true><<<grid, 256, 0, stream>>>(cls, loc, lmd, priors, targets,
                                                    keys, btv, bti, bc, npos, icnt, facc, P);
    } else {
        k_prior<32, false><<<grid, 256, 0, stream>>>(priors, targets, keys, btv, bti, P);
        k_match<32, false><<<grid, 256, 0, stream>>>(cls, loc, lmd, priors, targets,
                                                     keys, btv, bti, bc, npos, icnt, facc, P);
    }
    k_select<<<B, 1024, 0, stream>>>(bc, npos, facc, P);
    k_final<<<1, 64, 0, stream>>>(facc, icnt, (float*)d_out);
}